// Round 10
// baseline (82.247 us; speedup 1.0000x reference)
//
#include <hip/hip_runtime.h>
#include <math.h>

#define HH 32
#define WW 32
#define CIN 64
#define NO 64
#define NCK 576                 // CIN*9
#define X_ELEMS 262144

// ws float-offsets
#define WS_W   0                // Wz[ck][o] = -SZ*theta[o][ck]   (36864, coalesced in o)
#define WS_TAU 36864            // tau[ck] = SZ*min_o theta - 8, +64 pad(1e30)

__device__ __forceinline__ float fexp2(float x) {
#if __has_builtin(__builtin_amdgcn_exp2f)
    return __builtin_amdgcn_exp2f(x);
#else
    return exp2f(x);
#endif
}
__device__ __forceinline__ float flog2(float x) {
#if __has_builtin(__builtin_amdgcn_logf)
    return __builtin_amdgcn_logf(x);
#else
    return log2f(x);
#endif
}

__global__ __launch_bounds__(256) void prep_kernel(const float* __restrict__ theta,
                                                   float* __restrict__ ws) {
    const int b = blockIdx.x, t = threadIdx.x;
    constexpr float SZ = 19.235933878519512f;    // log2(e)/0.075
    if (b < 144) {                               // Wz transform (transposed)
        int i = b * 256 + t;                     // i = ck*64 + o
        int o = i & 63, ck = i >> 6;
        ws[WS_W + i] = -SZ * theta[o * NCK + ck];
    } else {                                     // tau + pad
        int idx = (b - 144) * 256 + t;
        if (idx < NCK) {
            float mn = 1e30f;
            for (int o = 0; o < NO; ++o) mn = fminf(mn, theta[o * NCK + idx]);
            ws[WS_TAU + idx] = SZ * mn - 8.0f;   // active iff z >= -8
        } else if (idx < NCK + 64) {
            ws[WS_TAU + idx] = 1e30f;            // pad: never active
        }
    }
}

// lane = output channel o; block = 128 thr = 2 waves = one pixel, c-split 32+32.
// Lanes 0..62 test 7 channels x 9 taps at once; ballot -> scalar mask; active
// taps processed 4 per round (depth-4 W-load pipeline). Body evaluates g
// directly with exp2/log2 (full VALU rate on gfx950 -- R4 evidence); no LDS.
// Disabled slots steer z=-200 -> exp2=0 -> exactly zero contribution.
__global__ __launch_bounds__(128) void ekv_kernel(
        const float* __restrict__ x, const float* __restrict__ ws,
        float* __restrict__ out) {
    constexpr float SZ = 19.235933878519512f;    // log2(e)/0.075
    constexpr float C2 = 1.2726342e-3f;          // 2^(-D2), D2 = 0.5/(0.075*ln2)
    constexpr float OS = 0.020018875579925058f;  // ln2^2 * 2e-6 * 500000/24

    __shared__ float part[64];

    const int t    = threadIdx.x;
    const int lane = t & 63;
    const int wv   = __builtin_amdgcn_readfirstlane(t >> 6);
    const int pix  = (int)blockIdx.x;
    const int n  = pix >> 10;
    const int ho = (pix >> 5) & 31;
    const int wo = pix & 31;
    const int c0 = wv * 32;

    // lane l -> (c_off = l/9, tap k = l%9); lane 63 decode-clamped + masked
    int l = lane;
    int c_off = l / 9; if (c_off > 6) c_off = 6;
    int k = l - 9 * c_off; if (k > 8) k = 8;
    int di = k / 3, dj = k - 3 * (k / 3);
    int h = ho + di - 1, w_ = wo + dj - 1;
    bool sval = (h >= 0) && (h < HH) && (w_ >= 0) && (w_ < WW);
    int hc = min(max(h, 0), HH - 1), wc = min(max(w_, 0), WW - 1);
    // pad/dup lanes: xs = 0 -> below tau (tau ~ 40) -> inactive; if ever
    // active (tiny theta), body still computes the correct x=0 contribution.
    float msc = ((l < 63) && sval) ? SZ : 0.0f;

    int gidx = n * (CIN * HH * WW) + (c0 + c_off) * 1024 + hc * WW + wc;
    const float* tw  = ws + WS_TAU + c0 * 9;
    const float* wsW = ws + WS_W;

    float accF = 0.f, accR = 0.f;

    float xv = x[min(gidx, X_ELEMS - 1)];    // chunk 0 gather (OOB lanes masked)
    float tv = tw[l];

    for (int cb = 0; cb < 32; cb += 7) {
        int cc = 32 - cb; if (cc > 7) cc = 7;
        // prefetch next chunk's gathers before processing this one
        int gidx2 = gidx + 7 * 1024;
        const float* tw2 = tw + 63;
        float xvn = xv, tvn = tv;
        if (cb + 7 < 32) { xvn = x[min(gidx2, X_ELEMS - 1)]; tvn = tw2[l]; }

        float xs = xv * msc;                         // SZ * x  (0 for pad lanes)
        unsigned long long act = __ballot(xs >= tv);
        act &= (1ull << (cc * 9)) - 1ull;            // kill out-of-chunk lanes

        const int cb9 = (c0 + cb) * 9;               // ck = cb9 + l
        while (act) {
            unsigned long long a = act;
            int i0 = (int)__builtin_ctzll(a);             a &= a - 1;
            bool h1 = a != 0;
            int i1 = a ? (int)__builtin_ctzll(a) : 0;     a &= a - 1;
            bool h2 = a != 0;
            int i2 = a ? (int)__builtin_ctzll(a) : 0;     a &= a - 1;
            bool h3 = a != 0;
            int i3 = a ? (int)__builtin_ctzll(a) : 0;     a &= a - 1;
            act = a;
            // issue all 4 W-row loads (coalesced 256B each) before any body
            float W0 = wsW[((cb9 + i0) << 6) + lane];
            float W1 = wsW[((cb9 + i1) << 6) + lane];
            float W2 = wsW[((cb9 + i2) << 6) + lane];
            float W3 = wsW[((cb9 + i3) << 6) + lane];

#define EKV_BODY(II, WV, EN)                                               \
            {                                                              \
                int xb = __builtin_amdgcn_readlane(                        \
                             __builtin_bit_cast(int, xs), (II));           \
                float sx = __builtin_bit_cast(float, xb);                  \
                float z  = (EN) ? (WV) + sx : -200.0f;  /* SZ*(x-theta) */ \
                float e  = fexp2(z);                                       \
                float f  = flog2(1.0f + e);                                \
                float r  = flog2(fmaf(C2, e, 1.0f));                       \
                accF = fmaf(f, f, accF);                                   \
                accR = fmaf(r, r, accR);                                   \
            }
            EKV_BODY(i0, W0, true)
            EKV_BODY(i1, W1, h1)
            EKV_BODY(i2, W2, h2)
            EKV_BODY(i3, W3, h3)
#undef EKV_BODY
        }
        gidx = gidx2; tw = tw2; xv = xvn; tv = tvn;
    }

    float p = accF - accR;
    if (wv == 1) part[lane] = p;
    __syncthreads();
    if (wv == 0)
        out[((n * NO + lane) * HH + ho) * WW + wo] = (p + part[lane]) * OS;
}

extern "C" void kernel_launch(void* const* d_in, const int* in_sizes, int n_in,
                              void* d_out, int out_size, void* d_ws, size_t ws_size,
                              hipStream_t stream) {
    const float* x     = (const float*)d_in[0];   // (4,64,32,32) fp32
    const float* theta = (const float*)d_in[1];   // (64,64,3,3) fp32
    float* out = (float*)d_out;                   // (4,64,32,32) fp32
    float* ws  = (float*)d_ws;

    prep_kernel<<<147, 256, 0, stream>>>(theta, ws);

    ekv_kernel<<<4096, 128, 0, stream>>>(x, ws, out); // 2 waves/pixel (c-split)
}

// Round 11
// 79.330 us; speedup vs baseline: 1.0368x; 1.0368x over previous
//
#include <hip/hip_runtime.h>
#include <math.h>

#define HH 32
#define WW 32
#define CIN 64
#define NO 64
#define NCK 576                 // CIN*9
#define X_ELEMS 262144

// ws float-offsets
#define WS_W    0               // Wz[ck][o] = -SZ*theta[o][ck]  (36864, coalesced in o)
#define WS_TAU  36864           // tau[ck] = SZ*min_o theta - 8, +64 pad(1e30)
#define WS_END  37504           // end of live region; [WS_END] = DCE dump slot

__device__ __forceinline__ float fexp2(float x) {
#if __has_builtin(__builtin_amdgcn_exp2f)
    return __builtin_amdgcn_exp2f(x);
#else
    return exp2f(x);
#endif
}
__device__ __forceinline__ float flog2(float x) {
#if __has_builtin(__builtin_amdgcn_logf)
    return __builtin_amdgcn_logf(x);
#else
    return log2f(x);
#endif
}

__global__ __launch_bounds__(256) void prep_kernel(const float* __restrict__ theta,
                                                   float* __restrict__ ws) {
    constexpr float SZ = 19.235933878519512f;    // log2(e)/0.075
    const int b = blockIdx.x, t = threadIdx.x;
    if (b < 144) {                               // W transform + in-wave tau min
        int i = b * 256 + t;                     // i = ck*64 + o; lanes are o
        int o = i & 63, ck = i >> 6;
        float th = theta[o * NCK + ck];
        ws[WS_W + i] = -SZ * th;
        float mn = th;                           // wave-min over the 64 o's
#pragma unroll
        for (int s = 32; s > 0; s >>= 1)
            mn = fminf(mn, __shfl_xor(mn, s, 64));
        if (o == 0) ws[WS_TAU + ck] = SZ * mn - 8.0f;   // active iff z >= -8
    } else {                                     // tau pad: never active
        if (t < 64) ws[WS_TAU + NCK + t] = 1e30f;
    }
}

// Pull ws (146 KB) + x (4 MB) into every XCD's L2. The harness's 268 MB d_ws
// re-poison before each timed launch evicts all of L3, so without this every
// W-row read chain in ekv starts at HBM-miss latency (~900 cy/round).
__global__ __launch_bounds__(256) void warm_kernel(const float* __restrict__ x,
                                                   float* __restrict__ ws) {
    const int gid = (int)blockIdx.x * 256 + (int)threadIdx.x;  // 128 blocks
    float acc = 0.f;
    const float4* w4 = (const float4*)ws;
    for (int i = gid; i < WS_END / 4; i += 128 * 256) acc += w4[i].x + w4[i].w;
    const float4* x4 = (const float4*)x;
    for (int i = gid; i < X_ELEMS / 4; i += 128 * 256) acc += x4[i].x + x4[i].w;
    if (acc == 1234.56789f) ws[WS_END] = acc;    // never true; defeats DCE
}

// lane = output channel o; block = 128 thr = 2 waves = one pixel, c-split 32+32.
// Lanes 0..62 test 7 channels x 9 taps at once; ballot -> scalar mask; active
// taps processed 4 per round (depth-4 W-load pipeline). Body evaluates g
// directly with exp2/log2; disabled slots steer z=-200 -> exp2=0 -> zero.
__global__ __launch_bounds__(128) void ekv_kernel(
        const float* __restrict__ x, const float* __restrict__ ws,
        float* __restrict__ out) {
    constexpr float SZ = 19.235933878519512f;    // log2(e)/0.075
    constexpr float C2 = 1.2726342e-3f;          // 2^(-D2), D2 = 0.5/(0.075*ln2)
    constexpr float OS = 0.020018875579925058f;  // ln2^2 * 2e-6 * 500000/24

    __shared__ float part[64];

    const int t    = threadIdx.x;
    const int lane = t & 63;
    const int wv   = __builtin_amdgcn_readfirstlane(t >> 6);
    const int pix  = (int)blockIdx.x;
    const int n  = pix >> 10;
    const int ho = (pix >> 5) & 31;
    const int wo = pix & 31;
    const int c0 = wv * 32;

    // lane l -> (c_off = l/9, tap k = l%9); lane 63 decode-clamped + masked
    int l = lane;
    int c_off = l / 9; if (c_off > 6) c_off = 6;
    int k = l - 9 * c_off; if (k > 8) k = 8;
    int di = k / 3, dj = k - 3 * (k / 3);
    int h = ho + di - 1, w_ = wo + dj - 1;
    bool sval = (h >= 0) && (h < HH) && (w_ >= 0) && (w_ < WW);
    int hc = min(max(h, 0), HH - 1), wc = min(max(w_, 0), WW - 1);
    // pad/dup lanes: xs = 0 -> below tau -> inactive; if ever active (tiny
    // theta), body still computes the correct x=0 contribution.
    float msc = ((l < 63) && sval) ? SZ : 0.0f;

    int gidx = n * (CIN * HH * WW) + (c0 + c_off) * 1024 + hc * WW + wc;
    const float* tw  = ws + WS_TAU + c0 * 9;
    const float* wsW = ws + WS_W;

    float accF = 0.f, accR = 0.f;

    float xv = x[min(gidx, X_ELEMS - 1)];    // chunk 0 gather (OOB lanes masked)
    float tv = tw[l];

    for (int cb = 0; cb < 32; cb += 7) {
        int cc = 32 - cb; if (cc > 7) cc = 7;
        // prefetch next chunk's gathers before processing this one
        int gidx2 = gidx + 7 * 1024;
        const float* tw2 = tw + 63;
        float xvn = xv, tvn = tv;
        if (cb + 7 < 32) { xvn = x[min(gidx2, X_ELEMS - 1)]; tvn = tw2[l]; }

        float xs = xv * msc;                         // SZ * x  (0 for pad lanes)
        unsigned long long act = __ballot(xs >= tv);
        act &= (1ull << (cc * 9)) - 1ull;            // kill out-of-chunk lanes

        const int cb9 = (c0 + cb) * 9;               // ck = cb9 + l
        while (act) {
            unsigned long long a = act;
            int i0 = (int)__builtin_ctzll(a);             a &= a - 1;
            bool h1 = a != 0;
            int i1 = a ? (int)__builtin_ctzll(a) : 0;     a &= a - 1;
            bool h2 = a != 0;
            int i2 = a ? (int)__builtin_ctzll(a) : 0;     a &= a - 1;
            bool h3 = a != 0;
            int i3 = a ? (int)__builtin_ctzll(a) : 0;     a &= a - 1;
            act = a;
            // issue all 4 W-row loads (coalesced 256B each) before any body
            float W0 = wsW[((cb9 + i0) << 6) + lane];
            float W1 = wsW[((cb9 + i1) << 6) + lane];
            float W2 = wsW[((cb9 + i2) << 6) + lane];
            float W3 = wsW[((cb9 + i3) << 6) + lane];

#define EKV_BODY(II, WV, EN)                                               \
            {                                                              \
                int xb = __builtin_amdgcn_readlane(                        \
                             __builtin_bit_cast(int, xs), (II));           \
                float sx = __builtin_bit_cast(float, xb);                  \
                float z  = (EN) ? (WV) + sx : -200.0f;  /* SZ*(x-theta) */ \
                float e  = fexp2(z);                                       \
                float f  = flog2(1.0f + e);                                \
                float r  = flog2(fmaf(C2, e, 1.0f));                       \
                accF = fmaf(f, f, accF);                                   \
                accR = fmaf(r, r, accR);                                   \
            }
            EKV_BODY(i0, W0, true)
            EKV_BODY(i1, W1, h1)
            EKV_BODY(i2, W2, h2)
            EKV_BODY(i3, W3, h3)
#undef EKV_BODY
        }
        gidx = gidx2; tw = tw2; xv = xvn; tv = tvn;
    }

    float p = accF - accR;
    if (wv == 1) part[lane] = p;
    __syncthreads();
    if (wv == 0)
        out[((n * NO + lane) * HH + ho) * WW + wo] = (p + part[lane]) * OS;
}

extern "C" void kernel_launch(void* const* d_in, const int* in_sizes, int n_in,
                              void* d_out, int out_size, void* d_ws, size_t ws_size,
                              hipStream_t stream) {
    const float* x     = (const float*)d_in[0];   // (4,64,32,32) fp32
    const float* theta = (const float*)d_in[1];   // (64,64,3,3) fp32
    float* out = (float*)d_out;                   // (4,64,32,32) fp32
    float* ws  = (float*)d_ws;

    prep_kernel<<<145, 256, 0, stream>>>(theta, ws);
    warm_kernel<<<128, 256, 0, stream>>>(x, ws);      // spread ws+x into all XCD L2s
    ekv_kernel<<<4096, 128, 0, stream>>>(x, ws, out); // 2 waves/pixel (c-split)
}

// Round 12
// 78.015 us; speedup vs baseline: 1.0542x; 1.0169x over previous
//
#include <hip/hip_runtime.h>
#include <math.h>

#define HH 32
#define WW 32
#define CIN 64
#define NO 64
#define NCK 576                 // CIN*9
#define X_ELEMS 262144

// ws float-offsets
#define WS_W    0               // Wz[ck][o] = -SZ*theta[o][ck]  (36864, coalesced in o)
#define WS_TAU  36864           // tau[ck] = SZ*min_o theta - 8, +64 pad(1e30)
#define WS_END  37504           // end of live region; [WS_END] = DCE dump slot

// x tile: 68 channel-slots (64 + chunk-overrun slack) x 3h x 6w, zero-padded
#define TC 68
#define TILE_N (TC * 18)        // 1224 floats

__device__ __forceinline__ float fexp2(float x) {
#if __has_builtin(__builtin_amdgcn_exp2f)
    return __builtin_amdgcn_exp2f(x);
#else
    return exp2f(x);
#endif
}
__device__ __forceinline__ float flog2(float x) {
#if __has_builtin(__builtin_amdgcn_logf)
    return __builtin_amdgcn_logf(x);
#else
    return log2f(x);
#endif
}

__global__ __launch_bounds__(256) void prep_kernel(const float* __restrict__ theta,
                                                   float* __restrict__ ws) {
    constexpr float SZ = 19.235933878519512f;    // log2(e)/0.075
    const int b = blockIdx.x, t = threadIdx.x;
    if (b < 144) {                               // W transform + in-wave tau min
        int i = b * 256 + t;                     // i = ck*64 + o; lanes are o
        int o = i & 63, ck = i >> 6;
        float th = theta[o * NCK + ck];
        ws[WS_W + i] = -SZ * th;
        float mn = th;                           // wave-min over the 64 o's
#pragma unroll
        for (int s = 32; s > 0; s >>= 1)
            mn = fminf(mn, __shfl_xor(mn, s, 64));
        if (o == 0) ws[WS_TAU + ck] = SZ * mn - 8.0f;   // active iff z >= -8
    } else {                                     // tau pad: never active
        if (t < 64) ws[WS_TAU + NCK + t] = 1e30f;
    }
}

// Pull ws (150 KB) into every XCD's L2 (harness's 268 MB d_ws poison evicts L3).
__global__ __launch_bounds__(256) void warm_kernel(float* __restrict__ ws) {
    const int gid = (int)blockIdx.x * 256 + (int)threadIdx.x;  // 64 blocks
    float acc = 0.f;
    const float4* w4 = (const float4*)ws;
    for (int i = gid; i < WS_END / 4; i += 64 * 256) acc += w4[i].x + w4[i].w;
    if (acc == 1234.56789f) ws[WS_END] = acc;    // never true; defeats DCE
}

// Block = 512 thr = 8 waves = 4 adjacent pixels x 2 c-halves. Block stages the
// x window [64c][3h][6w] into LDS (zero-padded == reference's zero padding,
// so pad taps are exact). Wave: lane = o; lanes 0..62 test 7 ch x 9 taps per
// ballot; active taps processed 4/round with pipelined global W-row loads.
__global__ __launch_bounds__(512) void ekv_kernel(
        const float* __restrict__ x, const float* __restrict__ ws,
        float* __restrict__ out) {
    constexpr float SZ = 19.235933878519512f;    // log2(e)/0.075
    constexpr float C2 = 1.2726342e-3f;          // 2^(-D2), D2 = 0.5/(0.075*ln2)
    constexpr float OS = 0.020018875579925058f;  // ln2^2 * 2e-6 * 500000/24

    __shared__ float xt[TILE_N];
    __shared__ float part[4][64];

    const int t   = threadIdx.x;
    const int grp = (int)blockIdx.x;             // n(4) x ho(32) x wg8(8)
    const int n   = grp >> 8;
    const int ho  = (grp >> 3) & 31;
    const int wg  = (grp & 7) << 2;              // first of 4 pixels

    // ---- stage x window: idx = c*18 + hh*6 + ww ; h=ho-1+hh, w=wg-1+ww ----
#pragma unroll
    for (int pass = 0; pass < 3; ++pass) {
        int idx = pass * 512 + t;
        if (idx < TILE_N) {
            int c  = idx / 18, rem = idx - 18 * c;
            int hh = rem / 6,  ww2 = rem - 6 * hh;
            int h = ho - 1 + hh, w = wg - 1 + ww2;
            float v = 0.f;
            if (c < CIN && h >= 0 && h < HH && w >= 0 && w < WW)
                v = x[((n * CIN + c) * HH + h) * WW + w];
            xt[idx] = v;
        }
    }
    __syncthreads();

    const int lane = t & 63;
    const int wv   = __builtin_amdgcn_readfirstlane(t >> 6);  // 0..7
    const int px   = wv >> 1;                    // pixel within group
    const int half = wv & 1;                     // c-half
    const int c0   = half * 32;
    const int wo   = wg + px;

    // lane l -> (c_off = l/9, tap k = l%9); lane 63 decode-clamped, act-masked
    int l = lane;
    int c_off = l / 9; if (c_off > 6) c_off = 6;
    int k = l - 9 * c_off; if (k > 8) k = 8;
    int di = k / 3, dj = k - 3 * (k / 3);
    int loff = (c0 + c_off) * 18 + di * 6 + px + dj;  // LDS tile address

    const float* tw  = ws + WS_TAU + c0 * 9;
    const float* wsW = ws + WS_W;

    float accF = 0.f, accR = 0.f;

    float xv = xt[loff];                         // chunk 0 (LDS)
    float tv = tw[l];

    for (int cb = 0; cb < 32; cb += 7) {
        int cc = 32 - cb; if (cc > 7) cc = 7;
        // prefetch next chunk (LDS x + global tau) before processing this one
        int loff2 = loff + 7 * 18;
        const float* tw2 = tw + 63;
        float xvn = xv, tvn = tv;
        if (cb + 7 < 32) { xvn = xt[loff2]; tvn = tw2[l]; }

        float xs = xv * SZ;                          // SZ*x (pad taps: 0)
        unsigned long long act = __ballot(xs >= tv);
        act &= (1ull << (cc * 9)) - 1ull;            // kill out-of-chunk lanes

        const int cb9 = (c0 + cb) * 9;               // ck = cb9 + l
        while (act) {
            unsigned long long a = act;
            int i0 = (int)__builtin_ctzll(a);             a &= a - 1;
            bool h1 = a != 0;
            int i1 = a ? (int)__builtin_ctzll(a) : 0;     a &= a - 1;
            bool h2 = a != 0;
            int i2 = a ? (int)__builtin_ctzll(a) : 0;     a &= a - 1;
            bool h3 = a != 0;
            int i3 = a ? (int)__builtin_ctzll(a) : 0;     a &= a - 1;
            act = a;
            // issue all 4 W-row loads (coalesced 256B each) before any body
            float W0 = wsW[((cb9 + i0) << 6) + lane];
            float W1 = wsW[((cb9 + i1) << 6) + lane];
            float W2 = wsW[((cb9 + i2) << 6) + lane];
            float W3 = wsW[((cb9 + i3) << 6) + lane];

#define EKV_BODY(II, WV, EN)                                               \
            {                                                              \
                int xb = __builtin_amdgcn_readlane(                        \
                             __builtin_bit_cast(int, xs), (II));           \
                float sx = __builtin_bit_cast(float, xb);                  \
                float z  = (EN) ? (WV) + sx : -200.0f;  /* SZ*(x-theta) */ \
                float e  = fexp2(z);                                       \
                float f  = flog2(1.0f + e);                                \
                float r  = flog2(fmaf(C2, e, 1.0f));                       \
                accF = fmaf(f, f, accF);                                   \
                accR = fmaf(r, r, accR);                                   \
            }
            EKV_BODY(i0, W0, true)
            EKV_BODY(i1, W1, h1)
            EKV_BODY(i2, W2, h2)
            EKV_BODY(i3, W3, h3)
#undef EKV_BODY
        }
        loff = loff2; tw = tw2; xv = xvn; tv = tvn;
    }

    float p = accF - accR;
    if (half == 1) part[px][lane] = p;
    __syncthreads();
    if (half == 0)
        out[((n * NO + lane) * HH + ho) * WW + wo] = (p + part[px][lane]) * OS;
}

extern "C" void kernel_launch(void* const* d_in, const int* in_sizes, int n_in,
                              void* d_out, int out_size, void* d_ws, size_t ws_size,
                              hipStream_t stream) {
    const float* x     = (const float*)d_in[0];   // (4,64,32,32) fp32
    const float* theta = (const float*)d_in[1];   // (64,64,3,3) fp32
    float* out = (float*)d_out;                   // (4,64,32,32) fp32
    float* ws  = (float*)d_ws;

    prep_kernel<<<145, 256, 0, stream>>>(theta, ws);
    warm_kernel<<<64, 256, 0, stream>>>(ws);          // ws into all XCD L2s
    ekv_kernel<<<1024, 512, 0, stream>>>(x, ws, out); // 8 waves: 4 px x 2 c-halves
}